// Round 2
// baseline (911.897 us; speedup 1.0000x reference)
//
#include <hip/hip_runtime.h>
#include <hip/hip_bf16.h>

// ef = [P_src | P_tgt] gathered per edge; z = attn * (ef @ [Wa1|We]) + bias
// (attn scalar commutes past We). All GEMMs bf16 MFMA 16x16x32, fp32 accum.
// Wave w owns n-tiles {w+4k} so attn cols, GeGLU pairs (t,t+8) and LN g-cols
// are wave-local -> all-register epilogue. Final output staged through LDS
// (overlaid on the dead A-tile) so global stores are full 128B lines — the
// R1 direct per-lane stores caused 4x write amplification (RMW partial lines).

typedef __bf16 bf16x8 __attribute__((ext_vector_type(8)));
typedef float f32x4 __attribute__((ext_vector_type(4)));

__device__ __forceinline__ unsigned short f2b(float f) {
    unsigned int u = __float_as_uint(f);
    unsigned int r = (u + 0x7fffu + ((u >> 16) & 1u)) >> 16;  // RNE
    return (unsigned short)r;
}

// ---- kernel 0: pack weights bf16, transposed to [n][k] for contiguous B-frags
__global__ __launch_bounds__(256) void pack_weights(
    const float* __restrict__ Ws, const float* __restrict__ Wt,
    const float* __restrict__ Wa1, const float* __restrict__ We,
    unsigned short* __restrict__ Wp1, unsigned short* __restrict__ Wp2)
{
    int id = blockIdx.x * 256 + threadIdx.x;
    if (id < 32768) {                      // Wp1[256][128]: [Ws|Wt] cols
        int n = id >> 7, k = id & 127;
        float v = (n < 128) ? Ws[k * 128 + n] : Wt[k * 128 + (n - 128)];
        Wp1[id] = f2b(v);
    }
    if (id < 98304) {                      // Wp2[384][256]: [Wa1|We] cols
        int n = id >> 8, k = id & 255;
        float v = (n < 128) ? Wa1[k * 128 + n] : We[k * 256 + (n - 128)];
        Wp2[id] = f2b(v);
    }
}

// ---- kernel 1: P[node][0:128]=emb@Ws+bs, P[node][128:256]=emb@Wt+bt (bf16)
__global__ __launch_bounds__(256) void node_proj(
    const float* __restrict__ emb, const unsigned short* __restrict__ Wp1,
    const float* __restrict__ bs, const float* __restrict__ bt,
    unsigned short* __restrict__ P, int NN)
{
    __shared__ unsigned short Alds[16][136];  // +8 pad: 2-way bank alias = free
    int t = threadIdx.x;
    {
        int row = t >> 4, cp = (t & 15) * 8;
        int node = blockIdx.x * 16 + row;
        if (node >= NN) node = NN - 1;
        const float* sp = emb + (size_t)node * 128 + cp;
        float4 v0 = *(const float4*)sp;
        float4 v1 = *(const float4*)(sp + 4);
        union { uint4 u; unsigned short s[8]; } pk;
        pk.s[0] = f2b(v0.x); pk.s[1] = f2b(v0.y); pk.s[2] = f2b(v0.z); pk.s[3] = f2b(v0.w);
        pk.s[4] = f2b(v1.x); pk.s[5] = f2b(v1.y); pk.s[6] = f2b(v1.z); pk.s[7] = f2b(v1.w);
        *(uint4*)&Alds[row][cp] = pk.u;
    }
    __syncthreads();
    int wv = t >> 6, lane = t & 63, n15 = lane & 15, quad = lane >> 4;
    f32x4 z4 = {0.f, 0.f, 0.f, 0.f};
    f32x4 acc[4] = {z4, z4, z4, z4};
    for (int ks = 0; ks < 4; ++ks) {
        bf16x8 a = *(const bf16x8*)&Alds[n15][ks * 32 + quad * 8];
#pragma unroll
        for (int tl = 0; tl < 4; ++tl) {
            int n = (wv * 4 + tl) * 16 + n15;
            bf16x8 b = *(const bf16x8*)(Wp1 + n * 128 + ks * 32 + quad * 8);
            acc[tl] = __builtin_amdgcn_mfma_f32_16x16x32_bf16(a, b, acc[tl], 0, 0, 0);
        }
    }
#pragma unroll
    for (int tl = 0; tl < 4; ++tl) {
        int c = (wv * 4 + tl) * 16 + n15;
        float bias = (c < 128) ? bs[c] : bt[c - 128];
#pragma unroll
        for (int r = 0; r < 4; ++r) {
            int node = blockIdx.x * 16 + quad * 4 + r;
            if (node < NN) P[(size_t)node * 256 + c] = f2b(acc[tl][r] + bias);
        }
    }
}

// ---- kernel 2: per-edge fused attn-gate + edge MLP + GeGLU + LayerNorm
// 64 edges/block, 4 waves. Wave wv: m-tiles 0..3 x n-tiles {wv+4k, k=0..5}.
// MFMA C-layout: col = lane&15 (n15), row = quad*4 + reg. Row reductions =
// shfl_xor over n15; cross-wave sums via tiny LDS partial buffers (3 KB).
__global__ __launch_bounds__(256, 4) void edge_kernel(
    const int* __restrict__ eidx, const unsigned short* __restrict__ P,
    const unsigned short* __restrict__ Wp2,
    const float* __restrict__ ba1, const float* __restrict__ Wa2,
    const float* __restrict__ ba2, const float* __restrict__ be,
    const float* __restrict__ gamma, const float* __restrict__ beta,
    float* __restrict__ out, int E)
{
    __shared__ unsigned short Alds[64][264];  // 64 edges x 256 bf16 (+8 pad)
    __shared__ float attnP[4][64];            // [wave][m*16+row]: h.Wa2 partials
    __shared__ float lnP[4][2][64];           // [wave][s1|s2][m*16+row]
    int t = threadIdx.x;
    int base = blockIdx.x * 64;

    // stage ef tile: chunk c -> edge e=c>>5, part p=c&31; col offset = p*8
    // (p<16: src row of P, p>=16: tgt row; p*8 lands in [128,256) automatically)
#pragma unroll
    for (int i = 0; i < 8; ++i) {
        int c = t + i * 256;
        int e = c >> 5, p = c & 31;
        int ge = base + e; if (ge >= E) ge = E - 1;
        int node = (p < 16) ? eidx[ge] : eidx[E + ge];
        *(uint4*)&Alds[e][p * 8] = *(const uint4*)(P + (size_t)node * 256 + p * 8);
    }
    __syncthreads();

    int wv = t >> 6, lane = t & 63, n15 = lane & 15, quad = lane >> 4;
    f32x4 z4 = {0.f, 0.f, 0.f, 0.f};
    f32x4 acc[24];
#pragma unroll
    for (int i = 0; i < 24; ++i) acc[i] = z4;

    // GEMM: acc[n*4+m] = m-tile m x n-tile (wv + 4n). B frags contiguous per
    // tile: row base (wv+4n)*16 + n15 -> wbase + n*16384 shorts.
    const unsigned short* wbase = Wp2 + (size_t)(wv * 16 + n15) * 256 + quad * 8;
    for (int ks = 0; ks < 8; ++ks) {
        bf16x8 a[4];
#pragma unroll
        for (int m = 0; m < 4; ++m)
            a[m] = *(const bf16x8*)&Alds[m * 16 + n15][ks * 32 + quad * 8];
#pragma unroll
        for (int n = 0; n < 6; ++n) {
            bf16x8 b = *(const bf16x8*)(wbase + n * 16384 + ks * 32);
#pragma unroll
            for (int m = 0; m < 4; ++m)
                acc[n * 4 + m] = __builtin_amdgcn_mfma_f32_16x16x32_bf16(a[m], b, acc[n * 4 + m], 0, 0, 0);
        }
    }

    // ---- attn partial: tiles {wv, wv+4} cover 2/8 of cols [0,128)
    float ba2s = ba2[0];
    float ba1v[2], wa2v[2];
#pragma unroll
    for (int n = 0; n < 2; ++n) {
        int col = (wv + 4 * n) * 16 + n15;
        ba1v[n] = ba1[col]; wa2v[n] = Wa2[col];
    }
#pragma unroll
    for (int m = 0; m < 4; ++m) {
#pragma unroll
        for (int r = 0; r < 4; ++r) {
            float v = fmaxf(acc[m][r] + ba1v[0], 0.f) * wa2v[0]
                    + fmaxf(acc[4 + m][r] + ba1v[1], 0.f) * wa2v[1];
            v += __shfl_xor(v, 1); v += __shfl_xor(v, 2);
            v += __shfl_xor(v, 4); v += __shfl_xor(v, 8);
            if (n15 == m * 4 + r) attnP[wv][m * 16 + quad * 4 + r] = v;
        }
    }
    __syncthreads();

    float attn[4][4];
#pragma unroll
    for (int m = 0; m < 4; ++m) {
#pragma unroll
        for (int r = 0; r < 4; ++r) {
            int row = m * 16 + quad * 4 + r;
            float s = attnP[0][row] + attnP[1][row] + attnP[2][row] + attnP[3][row];
            attn[m][r] = 1.f / (1.f + expf(-(s + ba2s)));
        }
    }

    // ---- GeGLU in-register: zx tile (wv+8+4j) pairs zg tile (wv+16+4j),
    // both owned by this wave. g overwrites the zx acc slot.
    float bex[2], beg[2], gmv[2], btv[2];
#pragma unroll
    for (int j = 0; j < 2; ++j) {
        int col = wv * 16 + j * 64 + n15;
        bex[j] = be[col];       beg[j] = be[128 + col];
        gmv[j] = gamma[col];    btv[j] = beta[col];
    }
#pragma unroll
    for (int m = 0; m < 4; ++m) {
#pragma unroll
        for (int r = 0; r < 4; ++r) {
            float s1 = 0.f, s2 = 0.f;
#pragma unroll
            for (int j = 0; j < 2; ++j) {
                float zx = fmaf(attn[m][r], acc[(2 + j) * 4 + m][r], bex[j]);
                float zg = fmaf(attn[m][r], acc[(4 + j) * 4 + m][r], beg[j]);
                float g = zx * (0.5f * zg * (1.f + erff(zg * 0.70710678118f)));
                acc[(2 + j) * 4 + m][r] = g;
                s1 += g; s2 = fmaf(g, g, s2);
            }
            s1 += __shfl_xor(s1, 1); s1 += __shfl_xor(s1, 2);
            s1 += __shfl_xor(s1, 4); s1 += __shfl_xor(s1, 8);
            s2 += __shfl_xor(s2, 1); s2 += __shfl_xor(s2, 2);
            s2 += __shfl_xor(s2, 4); s2 += __shfl_xor(s2, 8);
            if (n15 == m * 4 + r) {
                lnP[wv][0][m * 16 + quad * 4 + r] = s1;
                lnP[wv][1][m * 16 + quad * 4 + r] = s2;
            }
        }
    }
    __syncthreads();

    // ---- LN finalize: normalized outputs -> Olds (overlaid on dead Alds;
    // [64][132] fp32 = 33792 B = sizeof(Alds)), MFMA-layout writes are a free
    // 2-way bank alias. Then coalesced full-row float4 copy-out: each store
    // instruction covers 4 KB of contiguous output -> full 128B lines, no RMW.
    float* Olds = (float*)Alds;
#pragma unroll
    for (int m = 0; m < 4; ++m) {
#pragma unroll
        for (int r = 0; r < 4; ++r) {
            int row = m * 16 + quad * 4 + r;
            float s1 = lnP[0][0][row] + lnP[1][0][row] + lnP[2][0][row] + lnP[3][0][row];
            float s2 = lnP[0][1][row] + lnP[1][1][row] + lnP[2][1][row] + lnP[3][1][row];
            float mu = s1 * 0.0078125f;
            float var = s2 * 0.0078125f - mu * mu;
            float rs = rsqrtf(var + 1e-5f);
            Olds[row * 132 + wv * 16 + n15]      = (acc[8 + m][r]  - mu) * rs * gmv[0] + btv[0];
            Olds[row * 132 + 64 + wv * 16 + n15] = (acc[12 + m][r] - mu) * rs * gmv[1] + btv[1];
        }
    }
    __syncthreads();

#pragma unroll
    for (int i = 0; i < 8; ++i) {
        int e = i * 8 + (t >> 5);
        int edge = base + e;
        if (edge < E) {
            int c = (t & 31) * 4;
            *(float4*)(out + (size_t)edge * 128 + c) = *(const float4*)&Olds[e * 132 + c];
        }
    }
}

extern "C" void kernel_launch(void* const* d_in, const int* in_sizes, int n_in,
                              void* d_out, int out_size, void* d_ws, size_t ws_size,
                              hipStream_t stream) {
    const float* emb  = (const float*)d_in[0];
    const int*   eidx = (const int*)d_in[1];
    const float* Ws   = (const float*)d_in[2];
    const float* bs   = (const float*)d_in[3];
    const float* Wt   = (const float*)d_in[4];
    const float* bt   = (const float*)d_in[5];
    const float* Wa1  = (const float*)d_in[6];
    const float* ba1  = (const float*)d_in[7];
    const float* Wa2  = (const float*)d_in[8];
    const float* ba2  = (const float*)d_in[9];
    const float* We   = (const float*)d_in[10];
    const float* be   = (const float*)d_in[11];
    const float* gam  = (const float*)d_in[12];
    const float* bet  = (const float*)d_in[13];
    float* out = (float*)d_out;
    int NN = in_sizes[0] / 128;
    int E  = in_sizes[1] / 2;
    unsigned short* Wp1 = (unsigned short*)d_ws;       // 64 KB
    unsigned short* Wp2 = Wp1 + 32768;                 // 192 KB
    unsigned short* P   = Wp2 + 98304;                 // 25.6 MB
    hipLaunchKernelGGL(pack_weights, dim3(384), dim3(256), 0, stream,
                       Ws, Wt, Wa1, We, Wp1, Wp2);
    hipLaunchKernelGGL(node_proj, dim3((NN + 15) / 16), dim3(256), 0, stream,
                       emb, Wp1, bs, bt, P, NN);
    hipLaunchKernelGGL(edge_kernel, dim3((E + 63) / 64), dim3(256), 0, stream,
                       eidx, P, Wp2, ba1, Wa2, ba2, be, gam, bet, out, E);
}

// Round 3
// 571.597 us; speedup vs baseline: 1.5954x; 1.5954x over previous
//
#include <hip/hip_runtime.h>
#include <hip/hip_bf16.h>

// ef = [P_src | P_tgt] gathered per edge; z = attn * (ef @ [Wa1|We]) + bias
// (attn scalar commutes past We). All GEMMs bf16 MFMA 16x16x32, fp32 accum.
// Wave w owns n-tiles {w+4k}. TWO-PASS accumulation: pass 1 = attn tiles
// (k=0,1; 32 acc regs) -> attn scalar; pass 2 = zx/zg tiles (k=2..5; 64 acc
// regs, A re-read from LDS). Peak ~120 live regs -> __launch_bounds__(256,3)
// (170-reg budget) spills NOTHING. R1/R2's (256,4) cap forced scratch spills
// (VGPR_Count=64 vs ~200 live) = the phantom 1-1.5 GB of FETCH/WRITE traffic.
// Epilogue wave-local (no C staging); output staged via LDS for full-line
// stores.

typedef __bf16 bf16x8 __attribute__((ext_vector_type(8)));
typedef float f32x4 __attribute__((ext_vector_type(4)));

__device__ __forceinline__ unsigned short f2b(float f) {
    unsigned int u = __float_as_uint(f);
    unsigned int r = (u + 0x7fffu + ((u >> 16) & 1u)) >> 16;  // RNE
    return (unsigned short)r;
}

// ---- kernel 0: pack weights bf16, transposed to [n][k] for contiguous B-frags
__global__ __launch_bounds__(256) void pack_weights(
    const float* __restrict__ Ws, const float* __restrict__ Wt,
    const float* __restrict__ Wa1, const float* __restrict__ We,
    unsigned short* __restrict__ Wp1, unsigned short* __restrict__ Wp2)
{
    int id = blockIdx.x * 256 + threadIdx.x;
    if (id < 32768) {                      // Wp1[256][128]: [Ws|Wt] cols
        int n = id >> 7, k = id & 127;
        float v = (n < 128) ? Ws[k * 128 + n] : Wt[k * 128 + (n - 128)];
        Wp1[id] = f2b(v);
    }
    if (id < 98304) {                      // Wp2[384][256]: [Wa1|We] cols
        int n = id >> 8, k = id & 255;
        float v = (n < 128) ? Wa1[k * 128 + n] : We[k * 256 + (n - 128)];
        Wp2[id] = f2b(v);
    }
}

// ---- kernel 1: P[node][0:128]=emb@Ws+bs, P[node][128:256]=emb@Wt+bt (bf16)
__global__ __launch_bounds__(256) void node_proj(
    const float* __restrict__ emb, const unsigned short* __restrict__ Wp1,
    const float* __restrict__ bs, const float* __restrict__ bt,
    unsigned short* __restrict__ P, int NN)
{
    __shared__ unsigned short Alds[16][136];  // +8 pad: 2-way bank alias = free
    int t = threadIdx.x;
    {
        int row = t >> 4, cp = (t & 15) * 8;
        int node = blockIdx.x * 16 + row;
        if (node >= NN) node = NN - 1;
        const float* sp = emb + (size_t)node * 128 + cp;
        float4 v0 = *(const float4*)sp;
        float4 v1 = *(const float4*)(sp + 4);
        union { uint4 u; unsigned short s[8]; } pk;
        pk.s[0] = f2b(v0.x); pk.s[1] = f2b(v0.y); pk.s[2] = f2b(v0.z); pk.s[3] = f2b(v0.w);
        pk.s[4] = f2b(v1.x); pk.s[5] = f2b(v1.y); pk.s[6] = f2b(v1.z); pk.s[7] = f2b(v1.w);
        *(uint4*)&Alds[row][cp] = pk.u;
    }
    __syncthreads();
    int wv = t >> 6, lane = t & 63, n15 = lane & 15, quad = lane >> 4;
    f32x4 z4 = {0.f, 0.f, 0.f, 0.f};
    f32x4 acc[4] = {z4, z4, z4, z4};
    for (int ks = 0; ks < 4; ++ks) {
        bf16x8 a = *(const bf16x8*)&Alds[n15][ks * 32 + quad * 8];
#pragma unroll
        for (int tl = 0; tl < 4; ++tl) {
            int n = (wv * 4 + tl) * 16 + n15;
            bf16x8 b = *(const bf16x8*)(Wp1 + n * 128 + ks * 32 + quad * 8);
            acc[tl] = __builtin_amdgcn_mfma_f32_16x16x32_bf16(a, b, acc[tl], 0, 0, 0);
        }
    }
#pragma unroll
    for (int tl = 0; tl < 4; ++tl) {
        int c = (wv * 4 + tl) * 16 + n15;
        float bias = (c < 128) ? bs[c] : bt[c - 128];
#pragma unroll
        for (int r = 0; r < 4; ++r) {
            int node = blockIdx.x * 16 + quad * 4 + r;
            if (node < NN) P[(size_t)node * 256 + c] = f2b(acc[tl][r] + bias);
        }
    }
}

// ---- kernel 2: per-edge fused attn-gate + edge MLP + GeGLU + LayerNorm
// 64 edges/block, 4 waves. Wave wv: m-tiles 0..3 x n-tiles {wv+4k, k=0..5}.
// MFMA C-layout: col = lane&15 (n15), row = quad*4 + reg. Row reductions =
// shfl_xor over n15; cross-wave sums via tiny LDS partial buffers (3 KB).
__global__ __launch_bounds__(256, 3) void edge_kernel(
    const int* __restrict__ eidx, const unsigned short* __restrict__ P,
    const unsigned short* __restrict__ Wp2,
    const float* __restrict__ ba1, const float* __restrict__ Wa2,
    const float* __restrict__ ba2, const float* __restrict__ be,
    const float* __restrict__ gamma, const float* __restrict__ beta,
    float* __restrict__ out, int E)
{
    __shared__ unsigned short Alds[64][264];  // 64 edges x 256 bf16 (+8 pad)
    __shared__ float attnP[4][64];            // [wave][m*16+row]: h.Wa2 partials
    __shared__ float lnP[4][2][64];           // [wave][s1|s2][m*16+row]
    int t = threadIdx.x;
    int base = blockIdx.x * 64;

    // stage ef tile: chunk c -> edge e=c>>5, part p=c&31; col offset = p*8
    // (p<16: src row of P, p>=16: tgt row; p*8 lands in [128,256) automatically)
#pragma unroll
    for (int i = 0; i < 8; ++i) {
        int c = t + i * 256;
        int e = c >> 5, p = c & 31;
        int ge = base + e; if (ge >= E) ge = E - 1;
        int node = (p < 16) ? eidx[ge] : eidx[E + ge];
        *(uint4*)&Alds[e][p * 8] = *(const uint4*)(P + (size_t)node * 256 + p * 8);
    }
    __syncthreads();

    int wv = t >> 6, lane = t & 63, n15 = lane & 15, quad = lane >> 4;
    f32x4 z4 = {0.f, 0.f, 0.f, 0.f};
    const unsigned short* wbase = Wp2 + (size_t)(wv * 16 + n15) * 256 + quad * 8;

    // ======== PASS 1: attn tiles (n-tiles wv, wv+4) — 8 f32x4 acc ========
    f32x4 acc1[8];
#pragma unroll
    for (int i = 0; i < 8; ++i) acc1[i] = z4;
    for (int ks = 0; ks < 8; ++ks) {
        bf16x8 a[4];
#pragma unroll
        for (int m = 0; m < 4; ++m)
            a[m] = *(const bf16x8*)&Alds[m * 16 + n15][ks * 32 + quad * 8];
#pragma unroll
        for (int n = 0; n < 2; ++n) {
            bf16x8 b = *(const bf16x8*)(wbase + n * 16384 + ks * 32);
#pragma unroll
            for (int m = 0; m < 4; ++m)
                acc1[n * 4 + m] = __builtin_amdgcn_mfma_f32_16x16x32_bf16(a[m], b, acc1[n * 4 + m], 0, 0, 0);
        }
    }

    // attn partial: tiles {wv, wv+4} cover 2/8 of cols [0,128)
    float ba2s = ba2[0];
    float ba1v[2], wa2v[2];
#pragma unroll
    for (int n = 0; n < 2; ++n) {
        int col = (wv + 4 * n) * 16 + n15;
        ba1v[n] = ba1[col]; wa2v[n] = Wa2[col];
    }
#pragma unroll
    for (int m = 0; m < 4; ++m) {
#pragma unroll
        for (int r = 0; r < 4; ++r) {
            float v = fmaxf(acc1[m][r] + ba1v[0], 0.f) * wa2v[0]
                    + fmaxf(acc1[4 + m][r] + ba1v[1], 0.f) * wa2v[1];
            v += __shfl_xor(v, 1); v += __shfl_xor(v, 2);
            v += __shfl_xor(v, 4); v += __shfl_xor(v, 8);
            if (n15 == m * 4 + r) attnP[wv][m * 16 + quad * 4 + r] = v;
        }
    }
    __syncthreads();

    float attn[4][4];
#pragma unroll
    for (int m = 0; m < 4; ++m) {
#pragma unroll
        for (int r = 0; r < 4; ++r) {
            int row = m * 16 + quad * 4 + r;
            float s = attnP[0][row] + attnP[1][row] + attnP[2][row] + attnP[3][row];
            attn[m][r] = 1.f / (1.f + expf(-(s + ba2s)));
        }
    }

    // ======== PASS 2: zx/zg tiles (n-tiles wv+8..wv+20) — 16 f32x4 acc ====
    f32x4 acc2[16];
#pragma unroll
    for (int i = 0; i < 16; ++i) acc2[i] = z4;
    for (int ks = 0; ks < 8; ++ks) {
        bf16x8 a[4];
#pragma unroll
        for (int m = 0; m < 4; ++m)
            a[m] = *(const bf16x8*)&Alds[m * 16 + n15][ks * 32 + quad * 8];
#pragma unroll
        for (int j = 0; j < 4; ++j) {
            bf16x8 b = *(const bf16x8*)(wbase + (2 + j) * 16384 + ks * 32);
#pragma unroll
            for (int m = 0; m < 4; ++m)
                acc2[j * 4 + m] = __builtin_amdgcn_mfma_f32_16x16x32_bf16(a[m], b, acc2[j * 4 + m], 0, 0, 0);
        }
    }

    // ---- GeGLU in-register: zx tile (wv+8+4j) pairs zg tile (wv+16+4j),
    // both owned by this wave. g overwrites the zx acc slot.
    float bex[2], beg[2], gmv[2], btv[2];
#pragma unroll
    for (int j = 0; j < 2; ++j) {
        int col = wv * 16 + j * 64 + n15;
        bex[j] = be[col];       beg[j] = be[128 + col];
        gmv[j] = gamma[col];    btv[j] = beta[col];
    }
#pragma unroll
    for (int m = 0; m < 4; ++m) {
#pragma unroll
        for (int r = 0; r < 4; ++r) {
            float s1 = 0.f, s2 = 0.f;
#pragma unroll
            for (int j = 0; j < 2; ++j) {
                float zx = fmaf(attn[m][r], acc2[j * 4 + m][r], bex[j]);
                float zg = fmaf(attn[m][r], acc2[(2 + j) * 4 + m][r], beg[j]);
                float g = zx * (0.5f * zg * (1.f + erff(zg * 0.70710678118f)));
                acc2[j * 4 + m][r] = g;
                s1 += g; s2 = fmaf(g, g, s2);
            }
            s1 += __shfl_xor(s1, 1); s1 += __shfl_xor(s1, 2);
            s1 += __shfl_xor(s1, 4); s1 += __shfl_xor(s1, 8);
            s2 += __shfl_xor(s2, 1); s2 += __shfl_xor(s2, 2);
            s2 += __shfl_xor(s2, 4); s2 += __shfl_xor(s2, 8);
            if (n15 == m * 4 + r) {
                lnP[wv][0][m * 16 + quad * 4 + r] = s1;
                lnP[wv][1][m * 16 + quad * 4 + r] = s2;
            }
        }
    }
    __syncthreads();

    // ---- LN finalize: normalized outputs -> Olds (overlaid on dead Alds;
    // [64][132] fp32 = 33792 B = sizeof(Alds)); all Alds reads completed
    // before the barrier above. Then coalesced full-row float4 copy-out.
    float* Olds = (float*)Alds;
#pragma unroll
    for (int m = 0; m < 4; ++m) {
#pragma unroll
        for (int r = 0; r < 4; ++r) {
            int row = m * 16 + quad * 4 + r;
            float s1 = lnP[0][0][row] + lnP[1][0][row] + lnP[2][0][row] + lnP[3][0][row];
            float s2 = lnP[0][1][row] + lnP[1][1][row] + lnP[2][1][row] + lnP[3][1][row];
            float mu = s1 * 0.0078125f;
            float var = s2 * 0.0078125f - mu * mu;
            float rs = rsqrtf(var + 1e-5f);
            Olds[row * 132 + wv * 16 + n15]      = (acc2[m][r]     - mu) * rs * gmv[0] + btv[0];
            Olds[row * 132 + 64 + wv * 16 + n15] = (acc2[4 + m][r] - mu) * rs * gmv[1] + btv[1];
        }
    }
    __syncthreads();

#pragma unroll
    for (int i = 0; i < 8; ++i) {
        int e = i * 8 + (t >> 5);
        int edge = base + e;
        if (edge < E) {
            int c = (t & 31) * 4;
            *(float4*)(out + (size_t)edge * 128 + c) = *(const float4*)&Olds[e * 132 + c];
        }
    }
}

extern "C" void kernel_launch(void* const* d_in, const int* in_sizes, int n_in,
                              void* d_out, int out_size, void* d_ws, size_t ws_size,
                              hipStream_t stream) {
    const float* emb  = (const float*)d_in[0];
    const int*   eidx = (const int*)d_in[1];
    const float* Ws   = (const float*)d_in[2];
    const float* bs   = (const float*)d_in[3];
    const float* Wt   = (const float*)d_in[4];
    const float* bt   = (const float*)d_in[5];
    const float* Wa1  = (const float*)d_in[6];
    const float* ba1  = (const float*)d_in[7];
    const float* Wa2  = (const float*)d_in[8];
    const float* ba2  = (const float*)d_in[9];
    const float* We   = (const float*)d_in[10];
    const float* be   = (const float*)d_in[11];
    const float* gam  = (const float*)d_in[12];
    const float* bet  = (const float*)d_in[13];
    float* out = (float*)d_out;
    int NN = in_sizes[0] / 128;
    int E  = in_sizes[1] / 2;
    unsigned short* Wp1 = (unsigned short*)d_ws;       // 64 KB
    unsigned short* Wp2 = Wp1 + 32768;                 // 192 KB
    unsigned short* P   = Wp2 + 98304;                 // 25.6 MB
    hipLaunchKernelGGL(pack_weights, dim3(384), dim3(256), 0, stream,
                       Ws, Wt, Wa1, We, Wp1, Wp2);
    hipLaunchKernelGGL(node_proj, dim3((NN + 15) / 16), dim3(256), 0, stream,
                       emb, Wp1, bs, bt, P, NN);
    hipLaunchKernelGGL(edge_kernel, dim3((E + 63) / 64), dim3(256), 0, stream,
                       eidx, P, Wp2, ba1, Wa2, ba2, be, gam, bet, out, E);
}

// Round 4
// 551.669 us; speedup vs baseline: 1.6530x; 1.0361x over previous
//
#include <hip/hip_runtime.h>
#include <hip/hip_bf16.h>

// ef = [P_src | P_tgt] gathered per edge; z = attn * (ef @ [Wa1|We]) + bias
// (attn scalar commutes past We). All GEMMs bf16 MFMA 16x16x32, fp32 accum.
// edge_kernel: wave w owns n-tiles {w+4k}; two-pass accumulation (attn tiles
// then zx/zg tiles) keeps live regs ~120 -> (256,3) no spills (R2 lesson:
// capping below live set = scratch spill traffic masquerading as HBM).
// node_proj: 64 nodes/block, P-tile staged in LDS, full-row uint4 stores
// (old version: 12.8M scalar 2B stores = partial-line RMW + inst bound).
// erf via branch-free A&S 7.1.26 (libm erff is branchy, ~2x cost).

typedef __bf16 bf16x8 __attribute__((ext_vector_type(8)));
typedef float f32x4 __attribute__((ext_vector_type(4)));

__device__ __forceinline__ unsigned short f2b(float f) {
    unsigned int u = __float_as_uint(f);
    unsigned int r = (u + 0x7fffu + ((u >> 16) & 1u)) >> 16;  // RNE
    return (unsigned short)r;
}

// branch-free erf, |err| <= 1.5e-7 (Abramowitz-Stegun 7.1.26)
__device__ __forceinline__ float erf_fast(float x) {
    float ax = __builtin_fabsf(x);
    float t = __fdividef(1.f, fmaf(0.3275911f, ax, 1.f));
    float y = t * fmaf(t, fmaf(t, fmaf(t, fmaf(t, 1.061405429f, -1.453152027f),
                                       1.421413741f), -0.284496736f), 0.254829592f);
    float e = __expf(-ax * ax);
    float r = fmaf(-y, e, 1.f);
    return __builtin_copysignf(r, x);
}

// ---- kernel 0: pack weights bf16, transposed to [n][k] for contiguous B-frags
__global__ __launch_bounds__(256) void pack_weights(
    const float* __restrict__ Ws, const float* __restrict__ Wt,
    const float* __restrict__ Wa1, const float* __restrict__ We,
    unsigned short* __restrict__ Wp1, unsigned short* __restrict__ Wp2)
{
    int id = blockIdx.x * 256 + threadIdx.x;
    if (id < 32768) {                      // Wp1[256][128]: [Ws|Wt] cols
        int n = id >> 7, k = id & 127;
        float v = (n < 128) ? Ws[k * 128 + n] : Wt[k * 128 + (n - 128)];
        Wp1[id] = f2b(v);
    }
    if (id < 98304) {                      // Wp2[384][256]: [Wa1|We] cols
        int n = id >> 8, k = id & 255;
        float v = (n < 128) ? Wa1[k * 128 + n] : We[k * 256 + (n - 128)];
        Wp2[id] = f2b(v);
    }
}

// ---- kernel 1: P[node][0:128]=emb@Ws+bs, P[node][128:256]=emb@Wt+bt (bf16)
// 64 nodes/block, 4 waves. Wave wv owns n-tiles {wv+4k, k=0..3} x 4 m-tiles.
// A (64x128 bf16, stride 136) and P-tile (64x256 bf16, stride 264) share one
// 33792 B LDS buffer: A is dead after the GEMM barrier, P overlays it.
__global__ __launch_bounds__(256) void node_proj(
    const float* __restrict__ emb, const unsigned short* __restrict__ Wp1,
    const float* __restrict__ bs, const float* __restrict__ bt,
    unsigned short* __restrict__ P, int NN)
{
    __shared__ __align__(16) unsigned short SH[64 * 264];
    int t = threadIdx.x;
    int base = blockIdx.x * 64;

    // stage A: 1024 chunks of 8 floats -> bf16x8; chunk c: row=c>>4, cp=(c&15)*8
#pragma unroll
    for (int i = 0; i < 4; ++i) {
        int c = t + i * 256;
        int row = c >> 4, cp = (c & 15) * 8;
        int node = base + row; if (node >= NN) node = NN - 1;
        const float* sp = emb + (size_t)node * 128 + cp;
        float4 v0 = *(const float4*)sp;
        float4 v1 = *(const float4*)(sp + 4);
        union { uint4 u; unsigned short s[8]; } pk;
        pk.s[0] = f2b(v0.x); pk.s[1] = f2b(v0.y); pk.s[2] = f2b(v0.z); pk.s[3] = f2b(v0.w);
        pk.s[4] = f2b(v1.x); pk.s[5] = f2b(v1.y); pk.s[6] = f2b(v1.z); pk.s[7] = f2b(v1.w);
        *(uint4*)&SH[row * 136 + cp] = pk.u;
    }
    __syncthreads();

    int wv = t >> 6, lane = t & 63, n15 = lane & 15, quad = lane >> 4;
    f32x4 z4 = {0.f, 0.f, 0.f, 0.f};
    f32x4 acc[16];
#pragma unroll
    for (int i = 0; i < 16; ++i) acc[i] = z4;

    const unsigned short* wbase = Wp1 + (size_t)(wv * 16 + n15) * 128 + quad * 8;
    for (int ks = 0; ks < 4; ++ks) {
        bf16x8 a[4];
#pragma unroll
        for (int m = 0; m < 4; ++m)
            a[m] = *(const bf16x8*)&SH[(m * 16 + n15) * 136 + ks * 32 + quad * 8];
#pragma unroll
        for (int k = 0; k < 4; ++k) {
            bf16x8 b = *(const bf16x8*)(wbase + k * 8192 + ks * 32);
#pragma unroll
            for (int m = 0; m < 4; ++m)
                acc[k * 4 + m] = __builtin_amdgcn_mfma_f32_16x16x32_bf16(a[m], b, acc[k * 4 + m], 0, 0, 0);
        }
    }
    __syncthreads();   // all A reads done; SH becomes the P-tile

    // bias + pack into P-tile LDS (row stride 264 shorts)
#pragma unroll
    for (int k = 0; k < 4; ++k) {
        int colk = (wv + 4 * k) * 16 + n15;
        float bias = (colk < 128) ? bs[colk] : bt[colk - 128];
#pragma unroll
        for (int m = 0; m < 4; ++m) {
#pragma unroll
            for (int r = 0; r < 4; ++r)
                SH[(m * 16 + quad * 4 + r) * 264 + colk] = f2b(acc[k * 4 + m][r] + bias);
        }
    }
    __syncthreads();

    // copy out: 32 lanes x 16B = one full 512B node row per group, coalesced
#pragma unroll
    for (int i = 0; i < 8; ++i) {
        int e = i * 8 + (t >> 5);
        int node = base + e;
        if (node < NN) {
            int c = (t & 31) * 8;
            *(uint4*)(P + (size_t)node * 256 + c) = *(const uint4*)&SH[e * 264 + c];
        }
    }
}

// ---- kernel 2: per-edge fused attn-gate + edge MLP + GeGLU + LayerNorm
// 64 edges/block, 4 waves. Wave wv: m-tiles 0..3 x n-tiles {wv+4k, k=0..5}.
// MFMA C-layout: col = lane&15 (n15), row = quad*4 + reg. Row reductions =
// shfl_xor over n15; cross-wave sums via tiny LDS partial buffers (3 KB).
__global__ __launch_bounds__(256, 3) void edge_kernel(
    const int* __restrict__ eidx, const unsigned short* __restrict__ P,
    const unsigned short* __restrict__ Wp2,
    const float* __restrict__ ba1, const float* __restrict__ Wa2,
    const float* __restrict__ ba2, const float* __restrict__ be,
    const float* __restrict__ gamma, const float* __restrict__ beta,
    float* __restrict__ out, int E)
{
    __shared__ unsigned short Alds[64][264];  // 64 edges x 256 bf16 (+8 pad)
    __shared__ float attnP[4][64];            // [wave][m*16+row]: h.Wa2 partials
    __shared__ float lnP[4][2][64];           // [wave][s1|s2][m*16+row]
    int t = threadIdx.x;
    int base = blockIdx.x * 64;

    // stage ef tile: chunk c -> edge e=c>>5, part p=c&31; col offset = p*8
    // (p<16: src row of P, p>=16: tgt row; p*8 lands in [128,256) automatically)
#pragma unroll
    for (int i = 0; i < 8; ++i) {
        int c = t + i * 256;
        int e = c >> 5, p = c & 31;
        int ge = base + e; if (ge >= E) ge = E - 1;
        int node = (p < 16) ? eidx[ge] : eidx[E + ge];
        *(uint4*)&Alds[e][p * 8] = *(const uint4*)(P + (size_t)node * 256 + p * 8);
    }
    __syncthreads();

    int wv = t >> 6, lane = t & 63, n15 = lane & 15, quad = lane >> 4;
    f32x4 z4 = {0.f, 0.f, 0.f, 0.f};
    const unsigned short* wbase = Wp2 + (size_t)(wv * 16 + n15) * 256 + quad * 8;

    // ======== PASS 1: attn tiles (n-tiles wv, wv+4) — 8 f32x4 acc ========
    f32x4 acc1[8];
#pragma unroll
    for (int i = 0; i < 8; ++i) acc1[i] = z4;
    for (int ks = 0; ks < 8; ++ks) {
        bf16x8 a[4];
#pragma unroll
        for (int m = 0; m < 4; ++m)
            a[m] = *(const bf16x8*)&Alds[m * 16 + n15][ks * 32 + quad * 8];
#pragma unroll
        for (int n = 0; n < 2; ++n) {
            bf16x8 b = *(const bf16x8*)(wbase + n * 16384 + ks * 32);
#pragma unroll
            for (int m = 0; m < 4; ++m)
                acc1[n * 4 + m] = __builtin_amdgcn_mfma_f32_16x16x32_bf16(a[m], b, acc1[n * 4 + m], 0, 0, 0);
        }
    }

    // attn partial: tiles {wv, wv+4} cover 2/8 of cols [0,128)
    float ba2s = ba2[0];
    float ba1v[2], wa2v[2];
#pragma unroll
    for (int n = 0; n < 2; ++n) {
        int col = (wv + 4 * n) * 16 + n15;
        ba1v[n] = ba1[col]; wa2v[n] = Wa2[col];
    }
#pragma unroll
    for (int m = 0; m < 4; ++m) {
#pragma unroll
        for (int r = 0; r < 4; ++r) {
            float v = fmaxf(acc1[m][r] + ba1v[0], 0.f) * wa2v[0]
                    + fmaxf(acc1[4 + m][r] + ba1v[1], 0.f) * wa2v[1];
            v += __shfl_xor(v, 1); v += __shfl_xor(v, 2);
            v += __shfl_xor(v, 4); v += __shfl_xor(v, 8);
            if (n15 == m * 4 + r) attnP[wv][m * 16 + quad * 4 + r] = v;
        }
    }
    __syncthreads();

    float attn[4][4];
#pragma unroll
    for (int m = 0; m < 4; ++m) {
#pragma unroll
        for (int r = 0; r < 4; ++r) {
            int row = m * 16 + quad * 4 + r;
            float s = attnP[0][row] + attnP[1][row] + attnP[2][row] + attnP[3][row];
            attn[m][r] = __fdividef(1.f, 1.f + __expf(-(s + ba2s)));
        }
    }

    // ======== PASS 2: zx/zg tiles (n-tiles wv+8..wv+20) — 16 f32x4 acc ====
    f32x4 acc2[16];
#pragma unroll
    for (int i = 0; i < 16; ++i) acc2[i] = z4;
    for (int ks = 0; ks < 8; ++ks) {
        bf16x8 a[4];
#pragma unroll
        for (int m = 0; m < 4; ++m)
            a[m] = *(const bf16x8*)&Alds[m * 16 + n15][ks * 32 + quad * 8];
#pragma unroll
        for (int j = 0; j < 4; ++j) {
            bf16x8 b = *(const bf16x8*)(wbase + (2 + j) * 16384 + ks * 32);
#pragma unroll
            for (int m = 0; m < 4; ++m)
                acc2[j * 4 + m] = __builtin_amdgcn_mfma_f32_16x16x32_bf16(a[m], b, acc2[j * 4 + m], 0, 0, 0);
        }
    }

    // ---- GeGLU in-register: zx tile (wv+8+4j) pairs zg tile (wv+16+4j),
    // both owned by this wave. g overwrites the zx acc slot.
    float bex[2], beg[2], gmv[2], btv[2];
#pragma unroll
    for (int j = 0; j < 2; ++j) {
        int col = wv * 16 + j * 64 + n15;
        bex[j] = be[col];       beg[j] = be[128 + col];
        gmv[j] = gamma[col];    btv[j] = beta[col];
    }
#pragma unroll
    for (int m = 0; m < 4; ++m) {
#pragma unroll
        for (int r = 0; r < 4; ++r) {
            float s1 = 0.f, s2 = 0.f;
#pragma unroll
            for (int j = 0; j < 2; ++j) {
                float zx = fmaf(attn[m][r], acc2[j * 4 + m][r], bex[j]);
                float zg = fmaf(attn[m][r], acc2[(2 + j) * 4 + m][r], beg[j]);
                float g = zx * (0.5f * zg * (1.f + erf_fast(zg * 0.70710678118f)));
                acc2[j * 4 + m][r] = g;
                s1 += g; s2 = fmaf(g, g, s2);
            }
            s1 += __shfl_xor(s1, 1); s1 += __shfl_xor(s1, 2);
            s1 += __shfl_xor(s1, 4); s1 += __shfl_xor(s1, 8);
            s2 += __shfl_xor(s2, 1); s2 += __shfl_xor(s2, 2);
            s2 += __shfl_xor(s2, 4); s2 += __shfl_xor(s2, 8);
            if (n15 == m * 4 + r) {
                lnP[wv][0][m * 16 + quad * 4 + r] = s1;
                lnP[wv][1][m * 16 + quad * 4 + r] = s2;
            }
        }
    }
    __syncthreads();

    // ---- LN finalize: normalized outputs -> Olds (overlaid on dead Alds;
    // [64][132] fp32 = 33792 B = sizeof(Alds)); all Alds reads completed
    // before the barrier above. Then coalesced full-row float4 copy-out.
    float* Olds = (float*)Alds;
#pragma unroll
    for (int m = 0; m < 4; ++m) {
#pragma unroll
        for (int r = 0; r < 4; ++r) {
            int row = m * 16 + quad * 4 + r;
            float s1 = lnP[0][0][row] + lnP[1][0][row] + lnP[2][0][row] + lnP[3][0][row];
            float s2 = lnP[0][1][row] + lnP[1][1][row] + lnP[2][1][row] + lnP[3][1][row];
            float mu = s1 * 0.0078125f;
            float var = s2 * 0.0078125f - mu * mu;
            float rs = rsqrtf(var + 1e-5f);
            Olds[row * 132 + wv * 16 + n15]      = (acc2[m][r]     - mu) * rs * gmv[0] + btv[0];
            Olds[row * 132 + 64 + wv * 16 + n15] = (acc2[4 + m][r] - mu) * rs * gmv[1] + btv[1];
        }
    }
    __syncthreads();

#pragma unroll
    for (int i = 0; i < 8; ++i) {
        int e = i * 8 + (t >> 5);
        int edge = base + e;
        if (edge < E) {
            int c = (t & 31) * 4;
            *(float4*)(out + (size_t)edge * 128 + c) = *(const float4*)&Olds[e * 132 + c];
        }
    }
}

extern "C" void kernel_launch(void* const* d_in, const int* in_sizes, int n_in,
                              void* d_out, int out_size, void* d_ws, size_t ws_size,
                              hipStream_t stream) {
    const float* emb  = (const float*)d_in[0];
    const int*   eidx = (const int*)d_in[1];
    const float* Ws   = (const float*)d_in[2];
    const float* bs   = (const float*)d_in[3];
    const float* Wt   = (const float*)d_in[4];
    const float* bt   = (const float*)d_in[5];
    const float* Wa1  = (const float*)d_in[6];
    const float* ba1  = (const float*)d_in[7];
    const float* Wa2  = (const float*)d_in[8];
    const float* ba2  = (const float*)d_in[9];
    const float* We   = (const float*)d_in[10];
    const float* be   = (const float*)d_in[11];
    const float* gam  = (const float*)d_in[12];
    const float* bet  = (const float*)d_in[13];
    float* out = (float*)d_out;
    int NN = in_sizes[0] / 128;
    int E  = in_sizes[1] / 2;
    unsigned short* Wp1 = (unsigned short*)d_ws;       // 64 KB
    unsigned short* Wp2 = Wp1 + 32768;                 // 192 KB
    unsigned short* P   = Wp2 + 98304;                 // 25.6 MB
    hipLaunchKernelGGL(pack_weights, dim3(384), dim3(256), 0, stream,
                       Ws, Wt, Wa1, We, Wp1, Wp2);
    hipLaunchKernelGGL(node_proj, dim3((NN + 63) / 64), dim3(256), 0, stream,
                       emb, Wp1, bs, bt, P, NN);
    hipLaunchKernelGGL(edge_kernel, dim3((E + 63) / 64), dim3(256), 0, stream,
                       eidx, P, Wp2, ba1, Wa2, ba2, be, gam, bet, out, E);
}

// Round 5
// 542.879 us; speedup vs baseline: 1.6797x; 1.0162x over previous
//
#include <hip/hip_runtime.h>
#include <hip/hip_bf16.h>

// ef = [P_src | P_tgt] gathered per edge; z = attn * (ef @ [Wa1|We]) + bias
// (attn scalar commutes past We). All GEMMs bf16 MFMA 16x16x32, fp32 accum.
// edge_kernel: wave w owns n-tiles {w+4k}. THREE-pass accumulation (attn ->
// zg -> zx) keeps acc footprint small so B fragments can be PREFETCHED into
// registers inside latency-free windows (pass1 B under the gather+barrier,
// zg B under the attn reduce+sigmoid, zx B rotating 4-ahead). R4 showed the
// ks loops were un-pipelined (VGPR=80 of 168 budget): each ks paid ~200-400
// cyc of exposed L2 latency -> 40% pure stall. Reg peaks sized <=~155 so
// (256,3) spills nothing (R2 lesson: capped-below-live = scratch traffic).

typedef __bf16 bf16x8 __attribute__((ext_vector_type(8)));
typedef float f32x4 __attribute__((ext_vector_type(4)));

__device__ __forceinline__ unsigned short f2b(float f) {
    unsigned int u = __float_as_uint(f);
    unsigned int r = (u + 0x7fffu + ((u >> 16) & 1u)) >> 16;  // RNE
    return (unsigned short)r;
}

// branch-free erf, |err| <= 1.5e-7 (Abramowitz-Stegun 7.1.26)
__device__ __forceinline__ float erf_fast(float x) {
    float ax = __builtin_fabsf(x);
    float t = __fdividef(1.f, fmaf(0.3275911f, ax, 1.f));
    float y = t * fmaf(t, fmaf(t, fmaf(t, fmaf(t, 1.061405429f, -1.453152027f),
                                       1.421413741f), -0.284496736f), 0.254829592f);
    float e = __expf(-ax * ax);
    float r = fmaf(-y, e, 1.f);
    return __builtin_copysignf(r, x);
}

// ---- kernel 0: pack weights bf16, transposed to [n][k] for contiguous B-frags
__global__ __launch_bounds__(256) void pack_weights(
    const float* __restrict__ Ws, const float* __restrict__ Wt,
    const float* __restrict__ Wa1, const float* __restrict__ We,
    unsigned short* __restrict__ Wp1, unsigned short* __restrict__ Wp2)
{
    int id = blockIdx.x * 256 + threadIdx.x;
    if (id < 32768) {                      // Wp1[256][128]: [Ws|Wt] cols
        int n = id >> 7, k = id & 127;
        float v = (n < 128) ? Ws[k * 128 + n] : Wt[k * 128 + (n - 128)];
        Wp1[id] = f2b(v);
    }
    if (id < 98304) {                      // Wp2[384][256]: [Wa1|We] cols
        int n = id >> 8, k = id & 255;
        float v = (n < 128) ? Wa1[k * 128 + n] : We[k * 256 + (n - 128)];
        Wp2[id] = f2b(v);
    }
}

// ---- kernel 1: P[node][0:128]=emb@Ws+bs, P[node][128:256]=emb@Wt+bt (bf16)
// 64 nodes/block, 4 waves. Wave wv owns n-tiles {wv+4k, k=0..3} x 4 m-tiles.
// A (64x128 bf16, stride 136) and P-tile (64x256 bf16, stride 264) share one
// 33792 B LDS buffer. B frags prefetched pre-barrier (hidden under staging).
__global__ __launch_bounds__(256) void node_proj(
    const float* __restrict__ emb, const unsigned short* __restrict__ Wp1,
    const float* __restrict__ bs, const float* __restrict__ bt,
    unsigned short* __restrict__ P, int NN)
{
    __shared__ __align__(16) unsigned short SH[64 * 264];
    int t = threadIdx.x;
    int base = blockIdx.x * 64;

    // stage A: 1024 chunks of 8 floats -> bf16x8; chunk c: row=c>>4, cp=(c&15)*8
#pragma unroll
    for (int i = 0; i < 4; ++i) {
        int c = t + i * 256;
        int row = c >> 4, cp = (c & 15) * 8;
        int node = base + row; if (node >= NN) node = NN - 1;
        const float* sp = emb + (size_t)node * 128 + cp;
        float4 v0 = *(const float4*)sp;
        float4 v1 = *(const float4*)(sp + 4);
        union { uint4 u; unsigned short s[8]; } pk;
        pk.s[0] = f2b(v0.x); pk.s[1] = f2b(v0.y); pk.s[2] = f2b(v0.z); pk.s[3] = f2b(v0.w);
        pk.s[4] = f2b(v1.x); pk.s[5] = f2b(v1.y); pk.s[6] = f2b(v1.z); pk.s[7] = f2b(v1.w);
        *(uint4*)&SH[row * 136 + cp] = pk.u;
    }

    int wv = t >> 6, lane = t & 63, n15 = lane & 15, quad = lane >> 4;
    const unsigned short* wbase = Wp1 + (size_t)(wv * 16 + n15) * 128 + quad * 8;

    // prefetch all B frags (L2-resident) while the staging loads drain
    bf16x8 b[16];
#pragma unroll
    for (int k = 0; k < 4; ++k)
#pragma unroll
        for (int ks = 0; ks < 4; ++ks)
            b[k * 4 + ks] = *(const bf16x8*)(wbase + k * 8192 + ks * 32);

    __syncthreads();

    f32x4 z4 = {0.f, 0.f, 0.f, 0.f};
    f32x4 acc[16];
#pragma unroll
    for (int i = 0; i < 16; ++i) acc[i] = z4;

#pragma unroll
    for (int ks = 0; ks < 4; ++ks) {
        bf16x8 a[4];
#pragma unroll
        for (int m = 0; m < 4; ++m)
            a[m] = *(const bf16x8*)&SH[(m * 16 + n15) * 136 + ks * 32 + quad * 8];
#pragma unroll
        for (int k = 0; k < 4; ++k)
#pragma unroll
            for (int m = 0; m < 4; ++m)
                acc[k * 4 + m] = __builtin_amdgcn_mfma_f32_16x16x32_bf16(a[m], b[k * 4 + ks], acc[k * 4 + m], 0, 0, 0);
    }
    __syncthreads();   // all A reads done; SH becomes the P-tile

    // bias + pack into P-tile LDS (row stride 264 shorts)
#pragma unroll
    for (int k = 0; k < 4; ++k) {
        int colk = (wv + 4 * k) * 16 + n15;
        float bias = (colk < 128) ? bs[colk] : bt[colk - 128];
#pragma unroll
        for (int m = 0; m < 4; ++m) {
#pragma unroll
            for (int r = 0; r < 4; ++r)
                SH[(m * 16 + quad * 4 + r) * 264 + colk] = f2b(acc[k * 4 + m][r] + bias);
        }
    }
    __syncthreads();

    // copy out: 32 lanes x 16B = one full 512B node row per group, coalesced
#pragma unroll
    for (int i = 0; i < 8; ++i) {
        int e = i * 8 + (t >> 5);
        int node = base + e;
        if (node < NN) {
            int c = (t & 31) * 8;
            *(uint4*)(P + (size_t)node * 256 + c) = *(const uint4*)&SH[e * 264 + c];
        }
    }
}

// ---- kernel 2: per-edge fused attn-gate + edge MLP + GeGLU + LayerNorm
// 64 edges/block, 4 waves. Wave wv: m-tiles 0..3 x n-tiles {wv+4k, k=0..5}.
// MFMA C-layout: col = lane&15 (n15), row = quad*4 + reg. Row reductions =
// shfl_xor over n15; cross-wave sums via tiny LDS partial buffers (3 KB).
__global__ __launch_bounds__(256, 3) void edge_kernel(
    const int* __restrict__ eidx, const unsigned short* __restrict__ P,
    const unsigned short* __restrict__ Wp2,
    const float* __restrict__ ba1, const float* __restrict__ Wa2,
    const float* __restrict__ ba2, const float* __restrict__ be,
    const float* __restrict__ gamma, const float* __restrict__ beta,
    float* __restrict__ out, int E)
{
    __shared__ unsigned short Alds[64][264];  // 64 edges x 256 bf16 (+8 pad)
    __shared__ float attnP[4][64];            // [wave][m*16+row]: h.Wa2 partials
    __shared__ float lnP[4][2][64];           // [wave][s1|s2][m*16+row]
    int t = threadIdx.x;
    int base = blockIdx.x * 64;

    // stage ef tile: chunk c -> edge e=c>>5, part p=c&31; col offset = p*8
    // (p<16: src row of P, p>=16: tgt row; p*8 lands in [128,256) automatically)
#pragma unroll
    for (int i = 0; i < 8; ++i) {
        int c = t + i * 256;
        int e = c >> 5, p = c & 31;
        int ge = base + e; if (ge >= E) ge = E - 1;
        int node = (p < 16) ? eidx[ge] : eidx[E + ge];
        *(uint4*)&Alds[e][p * 8] = *(const uint4*)(P + (size_t)node * 256 + p * 8);
    }

    int wv = t >> 6, lane = t & 63, n15 = lane & 15, quad = lane >> 4;
    const unsigned short* wbase = Wp2 + (size_t)(wv * 16 + n15) * 256 + quad * 8;
    f32x4 z4 = {0.f, 0.f, 0.f, 0.f};

    // prefetch pass-1 B (attn tiles wv, wv+4): issued before the barrier,
    // latency hidden under the scattered gather above.
    bf16x8 b1[16];
#pragma unroll
    for (int ks = 0; ks < 8; ++ks) {
        b1[ks * 2]     = *(const bf16x8*)(wbase + 0 * 16384 + ks * 32);
        b1[ks * 2 + 1] = *(const bf16x8*)(wbase + 1 * 16384 + ks * 32);
    }

    __syncthreads();

    // ======== PASS 1: attn tiles — 8 f32x4 acc ========
    f32x4 acc1[8];
#pragma unroll
    for (int i = 0; i < 8; ++i) acc1[i] = z4;
#pragma unroll
    for (int ks = 0; ks < 8; ++ks) {
        bf16x8 a[4];
#pragma unroll
        for (int m = 0; m < 4; ++m)
            a[m] = *(const bf16x8*)&Alds[m * 16 + n15][ks * 32 + quad * 8];
#pragma unroll
        for (int n = 0; n < 2; ++n)
#pragma unroll
            for (int m = 0; m < 4; ++m)
                acc1[n * 4 + m] = __builtin_amdgcn_mfma_f32_16x16x32_bf16(a[m], b1[ks * 2 + n], acc1[n * 4 + m], 0, 0, 0);
    }

    // prefetch zg-tile B (tiles wv+16, wv+20): hidden under attn reduce +
    // barrier + sigmoid below. b1 is dead; allocator reuses its registers.
    bf16x8 bg[16];
#pragma unroll
    for (int ks = 0; ks < 8; ++ks) {
        bg[ks * 2]     = *(const bf16x8*)(wbase + 4 * 16384 + ks * 32);
        bg[ks * 2 + 1] = *(const bf16x8*)(wbase + 5 * 16384 + ks * 32);
    }

    // attn partial: tiles {wv, wv+4} cover 2/8 of cols [0,128)
    float ba2s = ba2[0];
    float ba1v[2], wa2v[2];
#pragma unroll
    for (int n = 0; n < 2; ++n) {
        int col = (wv + 4 * n) * 16 + n15;
        ba1v[n] = ba1[col]; wa2v[n] = Wa2[col];
    }
#pragma unroll
    for (int m = 0; m < 4; ++m) {
#pragma unroll
        for (int r = 0; r < 4; ++r) {
            float v = fmaxf(acc1[m][r] + ba1v[0], 0.f) * wa2v[0]
                    + fmaxf(acc1[4 + m][r] + ba1v[1], 0.f) * wa2v[1];
            v += __shfl_xor(v, 1); v += __shfl_xor(v, 2);
            v += __shfl_xor(v, 4); v += __shfl_xor(v, 8);
            if (n15 == m * 4 + r) attnP[wv][m * 16 + quad * 4 + r] = v;
        }
    }
    __syncthreads();

    float attn[4][4];
#pragma unroll
    for (int m = 0; m < 4; ++m) {
#pragma unroll
        for (int r = 0; r < 4; ++r) {
            int row = m * 16 + quad * 4 + r;
            float s = attnP[0][row] + attnP[1][row] + attnP[2][row] + attnP[3][row];
            attn[m][r] = __fdividef(1.f, 1.f + __expf(-(s + ba2s)));
        }
    }

    // ======== PASS ZG: gate tiles (wv+16, wv+20) — 8 f32x4 acc ========
    f32x4 accg[8];
#pragma unroll
    for (int i = 0; i < 8; ++i) accg[i] = z4;
#pragma unroll
    for (int ks = 0; ks < 8; ++ks) {
        bf16x8 a[4];
#pragma unroll
        for (int m = 0; m < 4; ++m)
            a[m] = *(const bf16x8*)&Alds[m * 16 + n15][ks * 32 + quad * 8];
#pragma unroll
        for (int n = 0; n < 2; ++n)
#pragma unroll
            for (int m = 0; m < 4; ++m)
                accg[n * 4 + m] = __builtin_amdgcn_mfma_f32_16x16x32_bf16(a[m], bg[ks * 2 + n], accg[n * 4 + m], 0, 0, 0);
    }

    // gg = 0.5*zg'*(1+erf(zg'/sqrt2)), zg' = attn*zg + be_gate  (accg dies)
    float bex[2], beg[2], gmv[2], btv[2];
#pragma unroll
    for (int j = 0; j < 2; ++j) {
        int col = wv * 16 + j * 64 + n15;
        bex[j] = be[col];       beg[j] = be[128 + col];
        gmv[j] = gamma[col];    btv[j] = beta[col];
    }
    f32x4 gg[8];
#pragma unroll
    for (int j = 0; j < 2; ++j)
#pragma unroll
        for (int m = 0; m < 4; ++m)
#pragma unroll
            for (int r = 0; r < 4; ++r) {
                float zg = fmaf(attn[m][r], accg[j * 4 + m][r], beg[j]);
                gg[j * 4 + m][r] = 0.5f * zg * (1.f + erf_fast(zg * 0.70710678118f));
            }

    // ======== PASS ZX: x tiles (wv+8, wv+12) — rotating 4-ahead B buffer ====
    bf16x8 bx[8];
#pragma unroll
    for (int ks = 0; ks < 4; ++ks) {
        bx[ks * 2]     = *(const bf16x8*)(wbase + 2 * 16384 + ks * 32);
        bx[ks * 2 + 1] = *(const bf16x8*)(wbase + 3 * 16384 + ks * 32);
    }
    f32x4 accx[8];
#pragma unroll
    for (int i = 0; i < 8; ++i) accx[i] = z4;
#pragma unroll
    for (int ks = 0; ks < 8; ++ks) {
        bf16x8 a[4];
#pragma unroll
        for (int m = 0; m < 4; ++m)
            a[m] = *(const bf16x8*)&Alds[m * 16 + n15][ks * 32 + quad * 8];
        bf16x8 bb0 = bx[(ks & 3) * 2], bb1 = bx[(ks & 3) * 2 + 1];
        if (ks < 4) {  // refill slot for ks+4 while this ks computes
            bx[(ks & 3) * 2]     = *(const bf16x8*)(wbase + 2 * 16384 + (ks + 4) * 32);
            bx[(ks & 3) * 2 + 1] = *(const bf16x8*)(wbase + 3 * 16384 + (ks + 4) * 32);
        }
#pragma unroll
        for (int m = 0; m < 4; ++m)
            accx[m] = __builtin_amdgcn_mfma_f32_16x16x32_bf16(a[m], bb0, accx[m], 0, 0, 0);
#pragma unroll
        for (int m = 0; m < 4; ++m)
            accx[4 + m] = __builtin_amdgcn_mfma_f32_16x16x32_bf16(a[m], bb1, accx[4 + m], 0, 0, 0);
    }

    // ---- GeGLU finalize + LN partial: g = (attn*zx+bex)*gg
#pragma unroll
    for (int m = 0; m < 4; ++m) {
#pragma unroll
        for (int r = 0; r < 4; ++r) {
            float s1 = 0.f, s2 = 0.f;
#pragma unroll
            for (int j = 0; j < 2; ++j) {
                float zx = fmaf(attn[m][r], accx[j * 4 + m][r], bex[j]);
                float g = zx * gg[j * 4 + m][r];
                accx[j * 4 + m][r] = g;
                s1 += g; s2 = fmaf(g, g, s2);
            }
            s1 += __shfl_xor(s1, 1); s1 += __shfl_xor(s1, 2);
            s1 += __shfl_xor(s1, 4); s1 += __shfl_xor(s1, 8);
            s2 += __shfl_xor(s2, 1); s2 += __shfl_xor(s2, 2);
            s2 += __shfl_xor(s2, 4); s2 += __shfl_xor(s2, 8);
            if (n15 == m * 4 + r) {
                lnP[wv][0][m * 16 + quad * 4 + r] = s1;
                lnP[wv][1][m * 16 + quad * 4 + r] = s2;
            }
        }
    }
    __syncthreads();

    // ---- LN finalize: normalized outputs -> Olds (overlaid on dead Alds;
    // [64][132] fp32 = 33792 B = sizeof(Alds)); all Alds reads completed
    // before the barrier above. Then coalesced full-row float4 copy-out.
    float* Olds = (float*)Alds;
#pragma unroll
    for (int m = 0; m < 4; ++m) {
#pragma unroll
        for (int r = 0; r < 4; ++r) {
            int row = m * 16 + quad * 4 + r;
            float s1 = lnP[0][0][row] + lnP[1][0][row] + lnP[2][0][row] + lnP[3][0][row];
            float s2 = lnP[0][1][row] + lnP[1][1][row] + lnP[2][1][row] + lnP[3][1][row];
            float mu = s1 * 0.0078125f;
            float var = s2 * 0.0078125f - mu * mu;
            float rs = rsqrtf(var + 1e-5f);
            Olds[row * 132 + wv * 16 + n15]      = (accx[m][r]     - mu) * rs * gmv[0] + btv[0];
            Olds[row * 132 + 64 + wv * 16 + n15] = (accx[4 + m][r] - mu) * rs * gmv[1] + btv[1];
        }
    }
    __syncthreads();

#pragma unroll
    for (int i = 0; i < 8; ++i) {
        int e = i * 8 + (t >> 5);
        int edge = base + e;
        if (edge < E) {
            int c = (t & 31) * 4;
            *(float4*)(out + (size_t)edge * 128 + c) = *(const float4*)&Olds[e * 132 + c];
        }
    }
}

extern "C" void kernel_launch(void* const* d_in, const int* in_sizes, int n_in,
                              void* d_out, int out_size, void* d_ws, size_t ws_size,
                              hipStream_t stream) {
    const float* emb  = (const float*)d_in[0];
    const int*   eidx = (const int*)d_in[1];
    const float* Ws   = (const float*)d_in[2];
    const float* bs   = (const float*)d_in[3];
    const float* Wt   = (const float*)d_in[4];
    const float* bt   = (const float*)d_in[5];
    const float* Wa1  = (const float*)d_in[6];
    const float* ba1  = (const float*)d_in[7];
    const float* Wa2  = (const float*)d_in[8];
    const float* ba2  = (const float*)d_in[9];
    const float* We   = (const float*)d_in[10];
    const float* be   = (const float*)d_in[11];
    const float* gam  = (const float*)d_in[12];
    const float* bet  = (const float*)d_in[13];
    float* out = (float*)d_out;
    int NN = in_sizes[0] / 128;
    int E  = in_sizes[1] / 2;
    unsigned short* Wp1 = (unsigned short*)d_ws;       // 64 KB
    unsigned short* Wp2 = Wp1 + 32768;                 // 192 KB
    unsigned short* P   = Wp2 + 98304;                 // 25.6 MB
    hipLaunchKernelGGL(pack_weights, dim3(384), dim3(256), 0, stream,
                       Ws, Wt, Wa1, We, Wp1, Wp2);
    hipLaunchKernelGGL(node_proj, dim3((NN + 63) / 64), dim3(256), 0, stream,
                       emb, Wp1, bs, bt, P, NN);
    hipLaunchKernelGGL(edge_kernel, dim3((E + 63) / 64), dim3(256), 0, stream,
                       eidx, P, Wp2, ba1, Wa2, ba2, be, gam, bet, out, E);
}